// Round 6
// baseline (626.026 us; speedup 1.0000x reference)
//
#include <hip/hip_runtime.h>

#define NB 8
#define NC 512
#define NPIX 4096
#define LOG2E 1.44269504088896340736f
#define C0TERM 28.853900817779268f   // 20*log2(e): p = exp2(s*log2e - C0TERM) = exp(s-20)

typedef __attribute__((ext_vector_type(4))) float f32x4;
typedef __attribute__((ext_vector_type(8))) short bf16x8;
typedef __attribute__((ext_vector_type(4))) unsigned short u16x4;

static __device__ __forceinline__ short f2bf(float f){
    union { float f; unsigned u; } v; v.f = f;
    unsigned r = v.u + 0x7fffu + ((v.u >> 16) & 1u);
    return (short)(r >> 16);
}

// ---------------- weight f32 -> bf16 ----------------
__global__ void k_wconv(const float* __restrict__ wq, const float* __restrict__ wk,
                        const float* __restrict__ wv,
                        short* __restrict__ wqb, short* __restrict__ wkb,
                        short* __restrict__ wvb){
    int i = blockIdx.x * 256 + threadIdx.x;
    if (i < 64*NC){ wqb[i] = f2bf(wq[i]); wkb[i] = f2bf(wk[i]); }
    if (i < NC*NC){ wvb[i] = f2bf(wv[i]); }
}

// ---------------- Q projection (O=64) ----------------
__global__ __launch_bounds__(256) void k_projq(const float* __restrict__ X,
                                               const short* __restrict__ W,
                                               const float* __restrict__ bias,
                                               short* __restrict__ out){
    const int b = blockIdx.y;
    const int wv = threadIdx.x >> 6;
    const int lane = threadIdx.x & 63;
    const int g = lane >> 4, c16 = lane & 15;
    const int n0w = blockIdx.x * 64 + wv * 16;
    const float* Xb = X + (size_t)b * NC * NPIX;

    f32x4 acc[4];
#pragma unroll
    for (int f = 0; f < 4; ++f) acc[f] = (f32x4){0.f,0.f,0.f,0.f};

    for (int c0 = 0; c0 < NC; c0 += 32){
        bf16x8 a;
#pragma unroll
        for (int j = 0; j < 8; ++j)
            a[j] = f2bf(Xb[(size_t)(c0 + 8*g + j) * NPIX + n0w + c16]);
#pragma unroll
        for (int f = 0; f < 4; ++f){
            bf16x8 bfr = *(const bf16x8*)(W + (size_t)(f*16 + c16) * NC + c0 + 8*g);
            acc[f] = __builtin_amdgcn_mfma_f32_16x16x32_bf16(a, bfr, acc[f], 0, 0, 0);
        }
    }
#pragma unroll
    for (int f = 0; f < 4; ++f){
        int o = f*16 + c16;
        float bo = bias[o];
#pragma unroll
        for (int i = 0; i < 4; ++i)
            out[((size_t)b*NPIX + n0w + 4*g + i)*64 + o] = f2bf(acc[f][i] + bo);
    }
}

// ---------------- fused K+V projection (one pass over view2) ----------------
__global__ __launch_bounds__(256) void k_projkv(const float* __restrict__ X,
                                                const short* __restrict__ Wv_,
                                                const float* __restrict__ bv_,
                                                const short* __restrict__ Wk_,
                                                const float* __restrict__ bk_,
                                                short* __restrict__ vout,
                                                short* __restrict__ kout){
    const int b = blockIdx.y;
    const int wv = threadIdx.x >> 6;
    const int lane = threadIdx.x & 63;
    const int g = lane >> 4, c16 = lane & 15;
    const int n0w = blockIdx.x * 32 + (wv & 1) * 16;
    const int oh = wv >> 1;
    const int o0v = oh * 256;
    const int o0k = oh * 32;
    const float* Xb = X + (size_t)b * NC * NPIX;

    f32x4 accv[16], acck[2];
#pragma unroll
    for (int f = 0; f < 16; ++f) accv[f] = (f32x4){0.f,0.f,0.f,0.f};
#pragma unroll
    for (int f = 0; f < 2;  ++f) acck[f] = (f32x4){0.f,0.f,0.f,0.f};

    for (int c0 = 0; c0 < NC; c0 += 32){
        bf16x8 a;
#pragma unroll
        for (int j = 0; j < 8; ++j)
            a[j] = f2bf(Xb[(size_t)(c0 + 8*g + j) * NPIX + n0w + c16]);
#pragma unroll
        for (int f = 0; f < 16; ++f){
            bf16x8 bfr = *(const bf16x8*)(Wv_ + (size_t)(o0v + f*16 + c16) * NC + c0 + 8*g);
            accv[f] = __builtin_amdgcn_mfma_f32_16x16x32_bf16(a, bfr, accv[f], 0, 0, 0);
        }
#pragma unroll
        for (int f = 0; f < 2; ++f){
            bf16x8 bfr = *(const bf16x8*)(Wk_ + (size_t)(o0k + f*16 + c16) * NC + c0 + 8*g);
            acck[f] = __builtin_amdgcn_mfma_f32_16x16x32_bf16(a, bfr, acck[f], 0, 0, 0);
        }
    }
#pragma unroll
    for (int f = 0; f < 16; ++f){
        int o = o0v + f*16 + c16;
        float bo = bv_[o];
        u16x4 pk;
#pragma unroll
        for (int i = 0; i < 4; ++i) pk[i] = (unsigned short)f2bf(accv[f][i] + bo);
        *(u16x4*)(vout + ((size_t)b*NC + o)*NPIX + n0w + 4*g) = pk;
    }
#pragma unroll
    for (int f = 0; f < 2; ++f){
        int o = o0k + f*16 + c16;
        float bo = bk_[o];
#pragma unroll
        for (int i = 0; i < 4; ++i)
            kout[((size_t)b*NPIX + n0w + 4*g + i)*64 + o] = f2bf(acck[f][i] + bo);
    }
}

// ---------------- fused attention, c-split for 2 blocks/CU ----------------
// Grid: 64 m-tiles x 2 c-halves x 8 batches = 1024 blocks; 8 waves each.
// Each block: m-tile 64, c-range [ch*256, ch*256+256) (QK duplicated across c-halves).
// compA roles (same as before): wave (wv&3)=m-sub, (wv>>2)=n-half -> P[64m][64n] in LDS.
// phaseB: wave covers c-sub = ch*256 + wv*32 (2 c-frags) -> acc 32 AGPRs.
// Iter order: issue V(t) -> compA(t+1) (K dbuf, ready) -> phaseB(t) (V arrived) -> barrier.
// __launch_bounds__(512,4): 128-reg budget; demand ~124 (acc32+kr32+vr16+q8+pa16+misc).
__global__ __launch_bounds__(512, 4) void k_attn(const short* __restrict__ qb,
                                                 const short* __restrict__ kb,
                                                 const short* __restrict__ vb,
                                                 const float* __restrict__ view1,
                                                 const float* __restrict__ gamma,
                                                 float* __restrict__ out){
    __shared__ __align__(16) short P[2][64*64];
    __shared__ float Lred[128];

    const int bid = blockIdx.x;
    const int b  = bid & 7;              // batch <-> XCD locality
    const int ch = (bid >> 3) & 1;       // c-half
    const int m0 = (bid >> 4) * 64;
    const int wv = threadIdx.x >> 6;
    const int lane = threadIdx.x & 63;
    const int g = lane >> 4, c16 = lane & 15;
    const int msubA = (wv & 3) * 16;
    const int nhalf = wv >> 2;
    const int c0w = ch * 256 + wv * 32;

    // Q fragment (B-operand of swapped mfma(K,Q)): lane c16 = m-col, k elems 8g+j
    const short* qrow = qb + ((size_t)b*NPIX + m0 + msubA + c16)*64 + 8*g;
    bf16x8 qa0 = *(const bf16x8*)qrow;
    bf16x8 qa1 = *(const bf16x8*)(qrow + 32);

    const size_t kbase = (size_t)b * NPIX * 64;
    const int mrow = msubA + c16;
    const int swz = (mrow & 7) << 4;
    float Lacc = 0.f;

    f32x4 acc[4][2];
#pragma unroll
    for (int f = 0; f < 4; ++f)
#pragma unroll
        for (int cf = 0; cf < 2; ++cf) acc[f][cf] = (f32x4){0.f,0.f,0.f,0.f};

    char* Pb0 = (char*)&P[0][0];
    char* Pb1 = (char*)&P[1][0];

    bf16x8 krA[4], krB[4], vr[4];

    auto loadK = [&](int t, bf16x8 (&kr)[4]){
        const short* kp = kb + kbase + (size_t)(t*64 + nhalf*32 + c16)*64 + 8*g;
        kr[0] = *(const bf16x8*)kp;
        kr[1] = *(const bf16x8*)(kp + 32);
        kr[2] = *(const bf16x8*)(kp + 16*64);
        kr[3] = *(const bf16x8*)(kp + 16*64 + 32);
    };
    auto loadV = [&](int t){
#pragma unroll
        for (int h = 0; h < 2; ++h)
#pragma unroll
            for (int cf = 0; cf < 2; ++cf)
                vr[h*2+cf] = *(const bf16x8*)(vb + ((size_t)b*NC + c0w + cf*16 + c16)*NPIX
                                              + t*64 + h*32 + 8*g);
    };

    auto compA = [&](const bf16x8 (&kr)[4], char* pb){
#pragma unroll
        for (int fn = 0; fn < 2; ++fn){
            f32x4 s = (f32x4){0.f,0.f,0.f,0.f};
            s = __builtin_amdgcn_mfma_f32_16x16x32_bf16(kr[fn*2+0], qa0, s, 0,0,0);
            s = __builtin_amdgcn_mfma_f32_16x16x32_bf16(kr[fn*2+1], qa1, s, 0,0,0);
            u16x4 pk;
#pragma unroll
            for (int i = 0; i < 4; ++i){
                float p = exp2f(fmaf(s[i], LOG2E, -C0TERM));
                Lacc += p;
                pk[i] = (unsigned short)f2bf(p);
            }
            int nrel0 = nhalf*32 + fn*16 + 4*g;
            *(u16x4*)(pb + mrow*128 + ((2*nrel0) ^ swz)) = pk;
        }
    };

    auto phaseB = [&](const char* pc){
#pragma unroll
        for (int h = 0; h < 2; ++h){
            bf16x8 pa[4];
#pragma unroll
            for (int f = 0; f < 4; ++f){
                int row = f*16 + c16;
                pa[f] = *(const bf16x8*)(pc + row*128 + ((h*64 + g*16) ^ ((row&7)<<4)));
            }
#pragma unroll
            for (int cf = 0; cf < 2; ++cf)
#pragma unroll
                for (int f = 0; f < 4; ++f)
                    acc[f][cf] = __builtin_amdgcn_mfma_f32_16x16x32_bf16(pa[f], vr[h*2+cf], acc[f][cf], 0,0,0);
        }
    };

    // iter(t): entry: kcur=K(t+1), P(t) in bufB. Computes P(t+1)->bufA, O += P(t)V(t).
    auto iter = [&](int t, char* bufA, const char* bufB,
                    const bf16x8 (&kcur)[4], bf16x8 (&knext)[4]){
        loadV(t);                                   // used by phaseB below (~350cy away)
        loadK(t+2 < 64 ? t+2 : 63, knext);          // used next iter
        compA(kcur, bufA);                          // MFMA + exp + pack + ds_write
        __builtin_amdgcn_s_setprio(1);
        phaseB(bufB);                               // V arrived during compA
        __builtin_amdgcn_s_setprio(0);
        asm volatile("s_waitcnt lgkmcnt(0)" ::: "memory");
        __builtin_amdgcn_s_barrier();
    };

    // prologue: K(0)->krA, P(0)->buf0; K(1)->krB
    loadK(0, krA);
    loadK(1, krB);
    compA(krA, Pb0);
    asm volatile("s_waitcnt lgkmcnt(0)" ::: "memory");
    __builtin_amdgcn_s_barrier();

    for (int t2 = 0; t2 < 31; ++t2){
        iter(2*t2,     Pb1, Pb0, krB, krA);
        iter(2*t2 + 1, Pb0, Pb1, krA, krB);
    }
    iter(62, Pb1, Pb0, krB, krA);
    // final: consume P(63), V(63)
    loadV(63);
    __builtin_amdgcn_s_setprio(1);
    phaseB(Pb1);
    __builtin_amdgcn_s_setprio(0);

    // ---- L reduction: per-lane partial covers (m=mrow, its n subset) ----
    Lacc += __shfl_xor(Lacc, 16);
    Lacc += __shfl_xor(Lacc, 32);
    if (lane < 16) Lred[nhalf*64 + msubA + lane] = Lacc;
    __syncthreads();

    // ---- epilogue: out = gamma * (O/L) + view1 ----
    float gm = gamma[0];
#pragma unroll
    for (int f = 0; f < 4; ++f){
        float sc[4];
#pragma unroll
        for (int i = 0; i < 4; ++i){
            int r = f*16 + 4*g + i;
            float Ls = Lred[r] + Lred[64 + r];
            sc[i] = gm / Ls;
        }
#pragma unroll
        for (int cf = 0; cf < 2; ++cf){
            int c = c0w + cf*16 + c16;
            size_t base = ((size_t)b*NC + c)*NPIX + m0 + f*16 + 4*g;
            f32x4 v1 = *(const f32x4*)(view1 + base);
            f32x4 r;
#pragma unroll
            for (int i = 0; i < 4; ++i) r[i] = sc[i]*acc[f][cf][i] + v1[i];
            *(f32x4*)(out + base) = r;
        }
    }
}

extern "C" void kernel_launch(void* const* d_in, const int* in_sizes, int n_in,
                              void* d_out, int out_size, void* d_ws, size_t ws_size,
                              hipStream_t stream){
    const float* view1 = (const float*)d_in[0];
    const float* view2 = (const float*)d_in[1];
    const float* Wq    = (const float*)d_in[2];
    const float* bq    = (const float*)d_in[3];
    const float* Wk    = (const float*)d_in[4];
    const float* bk    = (const float*)d_in[5];
    const float* Wv    = (const float*)d_in[6];
    const float* bv    = (const float*)d_in[7];
    const float* gamma = (const float*)d_in[8];
    float* out = (float*)d_out;

    char* ws = (char*)d_ws;
    short* qbuf = (short*)(ws);                                   // 4 MB  (B,N,64) bf16
    short* kbuf = (short*)(ws + (size_t)4*1024*1024);             // 4 MB  (B,N,64) bf16
    short* vbuf = (short*)(ws + (size_t)8*1024*1024);             // 32 MB (B,C,N) bf16
    short* wqb  = (short*)(ws + (size_t)40*1024*1024);            // 64 KB
    short* wkb  = (short*)(ws + (size_t)40*1024*1024 + 64*1024);  // 64 KB
    short* wvb  = (short*)(ws + (size_t)40*1024*1024 + 128*1024); // 512 KB

    hipLaunchKernelGGL(k_wconv, dim3(1024), dim3(256), 0, stream, Wq, Wk, Wv, wqb, wkb, wvb);
    hipLaunchKernelGGL(k_projq,  dim3(64, 8),  dim3(256), 0, stream, view1, wqb, bq, qbuf);
    hipLaunchKernelGGL(k_projkv, dim3(128, 8), dim3(256), 0, stream, view2, wvb, bv, wkb, bk, vbuf, kbuf);
    hipLaunchKernelGGL(k_attn,   dim3(1024), dim3(512), 0, stream, qbuf, kbuf, vbuf, view1, gamma, out);
}